// Round 12
// baseline (147.132 us; speedup 1.0000x reference)
//
#include <hip/hip_runtime.h>
#include <utility>

#define NQ 6
#define DIM 64

typedef float v2f __attribute__((ext_vector_type(2)));

namespace {

// ---- compile-time ring permutation (CNOT ladder), matching _ring_perm ----
constexpr int ring_entry(int r, int i) {
    int idx = i;
    for (int w = NQ - 1; w >= 0; --w) {
        int c = w;
        int t = (w + r) % NQ;
        int cbit = (idx >> (NQ - 1 - c)) & 1;
        idx ^= cbit << (NQ - 1 - t);
    }
    return idx;
}

// Logical->physical composed map after L rings (all rings are GF(2)-linear).
constexpr int Mc(int L, int i) {
    if (L == 1) return ring_entry(1, i);
    if (L == 2) return ring_entry(1, ring_entry(2, i));
    if (L == 3) return ring_entry(1, ring_entry(2, ring_entry(1, i)));
    return i;
}

constexpr int Minv(int L, int p) {
    for (int i = 0; i < DIM; ++i) if (Mc(L, i) == p) return i;
    return -1;
}

} // namespace

// ---- 1-instr VALU lane swap (pairs 2r<->2r+1): DPP quad_perm [1,0,3,2] ----
__device__ __forceinline__ float swap1(float v) {
    return __int_as_float(__builtin_amdgcn_mov_dpp(__float_as_int(v), 0xB1, 0xF, 0xF, true));
}
__device__ __forceinline__ v2f swap1v(v2f v) {
    v2f r; r.x = swap1(v.x); r.y = swap1(v.y); return r;
}
// (-v.y, v.x): the i* twiddle -- folds into VOP3P op_sel/neg on pk_fma
__device__ __forceinline__ v2f nsw(v2f v) {
    v2f r; r.x = -v.y; r.y = v.x; return r;
}

// ===== gate application in the fixed physical frame via composed maps =====
// 2 lanes per row: lane par = t&1 holds physical slots p = par*32 + l, l in [0,32).
// state: v2f sv[l] = (re, im) of slot l. logical i = Minv(L, p).

template<int LY, int W, int d, int... Ls>
__device__ __forceinline__ void wire_inlane(v2f* sv,
        float A0r, float A0i, float B0r, float B0i,
        float A1r, float A1i, float B1r, float B1i,
        std::integer_sequence<int, Ls...>) {
    (([&] {
        if constexpr (Ls < (Ls ^ d)) {
            constexpr int la = Ls, lb = Ls ^ d;
            constexpr int ra = (Minv(LY, la) >> (5 - W)) & 1;
            constexpr int rb = (Minv(LY, lb) >> (5 - W)) & 1;
            const float cAar = ra ? A1r : A0r, cAai = ra ? A1i : A0i;
            const float cBar = ra ? B1r : B0r, cBai = ra ? B1i : B0i;
            const float cAbr = rb ? A1r : A0r, cAbi = rb ? A1i : A0i;
            const float cBbr = rb ? B1r : B0r, cBbi = rb ? B1i : B0i;
            const v2f ma = sv[la], mb = sv[lb];
            const v2f na = nsw(ma), nb = nsw(mb);
            sv[la] = cAar*ma + cAai*na + cBar*mb + cBai*nb;
            sv[lb] = cAbr*mb + cAbi*nb + cBbr*ma + cBbi*na;
        }
    }()), ...);
}

template<int LY, int W, int... Ls>
__device__ __forceinline__ void wire_cross0(v2f* sv,
        float A0r, float A0i, float B0r, float B0i,
        float A1r, float A1i, float B1r, float B1i,
        std::integer_sequence<int, Ls...>) {
    (([&] {
        constexpr int r = (Minv(LY, Ls) >> (5 - W)) & 1;
        const float cAr = r ? A1r : A0r, cAi = r ? A1i : A0i;
        const float cBr = r ? B1r : B0r, cBi = r ? B1i : B0i;
        const v2f m = sv[Ls];
        const v2f t = swap1v(m);          // partner lane, same slot (old value)
        sv[Ls] = cAr*m + cAi*nsw(m) + cBr*t + cBi*nsw(t);
    }()), ...);
}

template<int LY, int W, int d, int... Ls>
__device__ __forceinline__ void wire_crossd(v2f* sv,
        float A0r, float A0i, float B0r, float B0i,
        float A1r, float A1i, float B1r, float B1i,
        std::integer_sequence<int, Ls...>) {
    (([&] {
        if constexpr (Ls < (Ls ^ d)) {
            constexpr int la = Ls, lb = Ls ^ d;
            constexpr int ra = (Minv(LY, la) >> (5 - W)) & 1;
            constexpr int rb = (Minv(LY, lb) >> (5 - W)) & 1;
            const float cAar = ra ? A1r : A0r, cAai = ra ? A1i : A0i;
            const float cBar = ra ? B1r : B0r, cBai = ra ? B1i : B0i;
            const float cAbr = rb ? A1r : A0r, cAbi = rb ? A1i : A0i;
            const float cBbr = rb ? B1r : B0r, cBbi = rb ? B1i : B0i;
            const v2f ma = sv[la], mb = sv[lb];
            const v2f ta = swap1v(mb);    // partner lane old [lb]
            const v2f tb = swap1v(ma);    // partner lane old [la]
            sv[la] = cAar*ma + cAai*nsw(ma) + cBar*ta + cBai*nsw(ta);
            sv[lb] = cAbr*mb + cAbi*nsw(mb) + cBbr*tb + cBbi*nsw(tb);
        }
    }()), ...);
}

template<int LY, int W>
__device__ __forceinline__ void wire_apply(v2f* sv,
        const float* __restrict__ g, bool par) {
    constexpr int D = Mc(LY, 1 << (5 - W));     // physical pair offset (linear map)
    constexpr bool cross = (D >> 5) & 1;
    constexpr int d = D & 31;
    constexpr bool cpar = (Minv(LY, 32) >> (5 - W)) & 1;  // role flips with parity

    float A0r, A0i, B0r, B0i, A1r, A1i, B1r, B1i;
    if constexpr (cpar) {
        A0r = par ? g[6] : g[0];  A0i = par ? g[7] : g[1];
        B0r = par ? g[4] : g[2];  B0i = par ? g[5] : g[3];
        A1r = par ? g[0] : g[6];  A1i = par ? g[1] : g[7];
        B1r = par ? g[2] : g[4];  B1i = par ? g[3] : g[5];
    } else {
        A0r = g[0]; A0i = g[1]; B0r = g[2]; B0i = g[3];
        A1r = g[6]; A1i = g[7]; B1r = g[4]; B1i = g[5];
    }
    if constexpr (!cross) {
        wire_inlane<LY, W, d>(sv, A0r, A0i, B0r, B0i, A1r, A1i, B1r, B1i,
                              std::make_integer_sequence<int, 32>{});
    } else if constexpr (d == 0) {
        wire_cross0<LY, W>(sv, A0r, A0i, B0r, B0i, A1r, A1i, B1r, B1i,
                           std::make_integer_sequence<int, 32>{});
    } else {
        wire_crossd<LY, W, d>(sv, A0r, A0i, B0r, B0i, A1r, A1i, B1r, B1i,
                              std::make_integer_sequence<int, 32>{});
    }
}

template<int LY>
__device__ __forceinline__ void layer_apply(v2f* sv,
        const float* __restrict__ g, bool par) {
    wire_apply<LY, 0>(sv, g,      par);
    wire_apply<LY, 1>(sv, g + 8,  par);
    wire_apply<LY, 2>(sv, g + 16, par);
    wire_apply<LY, 3>(sv, g + 24, par);
    wire_apply<LY, 4>(sv, g + 32, par);
    wire_apply<LY, 5>(sv, g + 40, par);
}

// ---- readout: fold full M3 into constexpr signs + one parity flip ----
template<int... Ls>
__device__ __forceinline__ void readout_impl(const v2f* sv, float* q,
                                             std::integer_sequence<int, Ls...>) {
    (([&] {
        constexpr int iv = Minv(3, Ls);
        const float pb = fmaf(sv[Ls].x, sv[Ls].x, sv[Ls].y * sv[Ls].y);
        q[0] += ((iv >> 5) & 1) ? -pb : pb;
        q[1] += ((iv >> 4) & 1) ? -pb : pb;
        q[2] += ((iv >> 3) & 1) ? -pb : pb;
        q[3] += ((iv >> 2) & 1) ? -pb : pb;
        q[4] += ((iv >> 1) & 1) ? -pb : pb;
        q[5] += ( iv       & 1) ? -pb : pb;
    }()), ...);
}

// ---- per-thread gate computation (fallback path only) ----
__device__ __forceinline__ void compute_gates6(const float* __restrict__ th, float* g) {
#pragma unroll
    for (int w = 0; w < NQ; ++w) {
        const float phi = th[w*3+0], theta = th[w*3+1], omega = th[w*3+2];
        float s, c, sa, ca, sb, cb;
        __sincosf(0.5f * theta, &s, &c);
        __sincosf(0.5f * (phi + omega), &sa, &ca);
        __sincosf(0.5f * (phi - omega), &sb, &cb);
        g[w*8+0] =  ca * c;  g[w*8+1] = -sa * c;
        g[w*8+2] = -cb * s;  g[w*8+3] = -sb * s;
        g[w*8+4] =  cb * s;  g[w*8+5] = -sb * s;
        g[w*8+6] =  ca * c;  g[w*8+7] =  sa * c;
    }
}

// ---- setup: gates (18x8) + Gt8[j] = {ln_g[j]*W2[m][j] (m<6), b1[j], 0} + C1/C2 ----
// ws floats: [0,144) gates, [144,656) Gt8 (j*8+m), [656,662) C1, [662,668) C2+b2
__global__ void setup_kernel(const float* __restrict__ th_s, const float* __restrict__ th_t,
                             const float* __restrict__ ln_g, const float* __restrict__ ln_b,
                             const float* __restrict__ W2, const float* __restrict__ b2,
                             const float* __restrict__ b1, float* __restrict__ ws) {
    const int t = threadIdx.x;
    if (t < 18) {
        const int l = t / 6, w = t % 6;
        const float* th = (l < 2) ? (th_s + (l * 6 + w) * 3) : (th_t + w * 3);
        const float phi = th[0], theta = th[1], omega = th[2];
        float s, c, sa, ca, sb, cb;
        sincosf(0.5f * theta, &s, &c);
        sincosf(0.5f * (phi + omega), &sa, &ca);
        sincosf(0.5f * (phi - omega), &sb, &cb);
        float* g = ws + t * 8;
        g[0] =  ca * c;  g[1] = -sa * c;
        g[2] = -cb * s;  g[3] = -sb * s;
        g[4] =  cb * s;  g[5] = -sb * s;
        g[6] =  ca * c;  g[7] =  sa * c;
    }
    if (t < 384) {
        const int j = t / 6, m = t % 6;
        ws[144 + j * 8 + m] = ln_g[j] * W2[m * 64 + j];
    }
    if (t < 64) {
        ws[144 + t * 8 + 6] = b1[t];
        ws[144 + t * 8 + 7] = 0.f;
    }
    if (t < 6) {
        float c1 = 0.f, c2 = 0.f;
        for (int j = 0; j < 64; ++j) {
            c1 += ln_g[j] * W2[t * 64 + j];
            c2 += ln_b[j] * W2[t * 64 + j];
        }
        ws[656 + t] = c1;
        ws[662 + t] = c2 + b2[t];
    }
}

template<bool USE_WS>
__global__ __launch_bounds__(256, 4)   // 128-VGPR budget: allocator fits naturally, no spill
void qmaml_kernel(
    const float* __restrict__ x,  const float* __restrict__ W1, const float* __restrict__ b1,
    const float* __restrict__ ln_g, const float* __restrict__ ln_b,
    const float* __restrict__ W2, const float* __restrict__ b2,
    const float* __restrict__ th_s, const float* __restrict__ th_t,
    const float* __restrict__ Wc, const float* __restrict__ bc,
    const float* __restrict__ ws, float* __restrict__ out, int nrows) {

    // ---- stage W1 into LDS (16 KB) ----
    __shared__ float4 wl[1024];
    {
        const float4* wg = (const float4*)W1;
        const int tid = threadIdx.x;
#pragma unroll
        for (int k = 0; k < 4; ++k) wl[tid + (k << 8)] = wg[tid + (k << 8)];
    }
    __syncthreads();

    const int t   = blockIdx.x * 256 + threadIdx.x;
    const int row = t >> 1;
    const bool par = t & 1;            // = logical wire-0 bit of my half-state
    if (row >= nrows) return;

    // ---- load the FULL x row (both lanes of the pair: same addresses) ----
    v2f xl[32];
    {
        const float4* xp = (const float4*)(x + (long)row * 64);
#pragma unroll
        for (int k = 0; k < 16; ++k) {
            const float4 v = xp[k];
            xl[2*k].x   = v.x; xl[2*k].y   = v.y;
            xl[2*k+1].x = v.z; xl[2*k+1].y = v.w;
        }
    }

    // ---- ROW-SPLIT matvec: lane par owns j in [32*par, 32*par+32) ----
    // Full dot per j (no cross-lane op inside the loop); relu/stats/A tail
    // executed once per j per PAIR; stats merged with 5 DPP+adds at the end.
    v2f A2[3]; A2[0] = 0.f; A2[1] = 0.f; A2[2] = 0.f;
    float A[6]  = {0.f, 0.f, 0.f, 0.f, 0.f, 0.f};
    float C1[6] = {0.f, 0.f, 0.f, 0.f, 0.f, 0.f};
    float C2[6] = {0.f, 0.f, 0.f, 0.f, 0.f, 0.f};
    float s = 0.f, s2 = 0.f;

    const int jbase = par << 5;
#pragma unroll 2
    for (int jj = 0; jj < 32; ++jj) {
        const int j = jbase + jj;
        const float4* wr = &wl[j * 16];
        v2f pa; pa = 0.f;
        v2f pb; pb = 0.f;
        v2f pc; pc = 0.f;
        v2f pd; pd = 0.f;
#pragma unroll
        for (int k = 0; k < 4; ++k) {
            const float4 a4 = wr[4*k+0];
            const float4 b4 = wr[4*k+1];
            const float4 c4 = wr[4*k+2];
            const float4 d4 = wr[4*k+3];
            v2f t0; t0.x = a4.x; t0.y = a4.y; pa = t0 * xl[8*k+0] + pa;
            v2f t1; t1.x = a4.z; t1.y = a4.w; pb = t1 * xl[8*k+1] + pb;
            v2f t2; t2.x = b4.x; t2.y = b4.y; pc = t2 * xl[8*k+2] + pc;
            v2f t3; t3.x = b4.z; t3.y = b4.w; pd = t3 * xl[8*k+3] + pd;
            v2f t4; t4.x = c4.x; t4.y = c4.y; pa = t4 * xl[8*k+4] + pa;
            v2f t5; t5.x = c4.z; t5.y = c4.w; pb = t5 * xl[8*k+5] + pb;
            v2f t6; t6.x = d4.x; t6.y = d4.y; pc = t6 * xl[8*k+6] + pc;
            v2f t7; t7.x = d4.z; t7.y = d4.w; pd = t7 * xl[8*k+7] + pd;
        }
        const v2f pv = (pa + pb) + (pc + pd);
        const float tot = pv.x + pv.y;
        if constexpr (USE_WS) {
            const v2f* Gt = (const v2f*)(ws + 144 + j * 8);
            const v2f g3 = Gt[3];                // (b1[j], 0)
            const float acc = fmaxf(tot + g3.x, 0.f);
            s += acc; s2 = fmaf(acc, acc, s2);
            A2[0] = acc * Gt[0] + A2[0];
            A2[1] = acc * Gt[1] + A2[1];
            A2[2] = acc * Gt[2] + A2[2];
        } else {
            const float acc = fmaxf(tot + b1[j], 0.f);
            s += acc; s2 = fmaf(acc, acc, s2);
            const float gj = ln_g[j], bj = ln_b[j];
#pragma unroll
            for (int m = 0; m < 6; ++m) {
                const float w2 = W2[m * 64 + j];
                const float gw = gj * w2;
                A[m]  = fmaf(acc, gw, A[m]);
                C1[m] += gw;
                C2[m] = fmaf(bj, w2, C2[m]);
            }
        }
    }
    // ---- pair-merge: total = mine + partner (bit-identical on both lanes) ----
    s  = s  + swap1(s);
    s2 = s2 + swap1(s2);
    if constexpr (USE_WS) {
        A2[0] = A2[0] + swap1v(A2[0]);
        A2[1] = A2[1] + swap1v(A2[1]);
        A2[2] = A2[2] + swap1v(A2[2]);
        A[0] = A2[0].x; A[1] = A2[0].y; A[2] = A2[1].x;
        A[3] = A2[1].y; A[4] = A2[2].x; A[5] = A2[2].y;
    } else {
#pragma unroll
        for (int m = 0; m < 6; ++m) {
            A[m]  = A[m]  + swap1(A[m]);
            C1[m] = C1[m] + swap1(C1[m]);
            C2[m] = C2[m] + swap1(C2[m]);
        }
    }

    const float mu  = s  * (1.f / 64.f);
    const float var = s2 * (1.f / 64.f) - mu * mu;
    const float inv = rsqrtf(var + 1e-5f);

    // ---- z = tanh(...), per-wire (cos, sin) ----
    float vc[6], vsn[6];
#pragma unroll
    for (int m = 0; m < 6; ++m) {
        float c1v, c2v;
        if constexpr (USE_WS) { c1v = ws[656 + m]; c2v = ws[662 + m]; }
        else                  { c1v = C1[m];       c2v = C2[m] + b2[m]; }
        const float zp = inv * (A[m] - mu * c1v) + c2v;
        const float e  = __expf(2.f * zp);
        const float z  = 1.f - 2.f / (e + 1.f);
        const float half = 1.57079632679f * z;
        vsn[m] = __sinf(half);
        vc[m]  = __cosf(half);
    }

    float gf[48];
    const float* g0;
    if constexpr (USE_WS) g0 = ws;      // wave-uniform -> SGPR s_loads
    else { compute_gates6(th_s, gf); g0 = gf; }

    // ---- build my 32 amps IN PLACE as packed complex ----
    v2f sv[32];
    {
        const float a0r = par ? (g0[4]*vc[0] + g0[6]*vsn[0]) : (g0[0]*vc[0] + g0[2]*vsn[0]);
        const float a0i = par ? (g0[5]*vc[0] + g0[7]*vsn[0]) : (g0[1]*vc[0] + g0[3]*vsn[0]);
        v2f ga1; ga1.x = g0[8]  * vc[1] + g0[10] * vsn[1];
                 ga1.y = g0[9]  * vc[1] + g0[11] * vsn[1];
        v2f gb1; gb1.x = g0[12] * vc[1] + g0[14] * vsn[1];
                 gb1.y = g0[13] * vc[1] + g0[15] * vsn[1];
        sv[0] = a0r * ga1 + a0i * nsw(ga1);
        sv[1] = a0r * gb1 + a0i * nsw(gb1);
    }
    {   // wire2: 2 -> 4
        v2f ya; ya.x = g0[16]*vc[2] + g0[18]*vsn[2]; ya.y = g0[17]*vc[2] + g0[19]*vsn[2];
        v2f yb; yb.x = g0[20]*vc[2] + g0[22]*vsn[2]; yb.y = g0[21]*vc[2] + g0[23]*vsn[2];
        const v2f nya = nsw(ya), nyb = nsw(yb);
#pragma unroll
        for (int k = 3; k >= 0; --k) {
            const v2f h = sv[k >> 1];
            const v2f y  = (k & 1) ? yb  : ya;
            const v2f ny = (k & 1) ? nyb : nya;
            sv[k] = h.x * y + h.y * ny;
        }
    }
    {   // wire3: 4 -> 8
        v2f ya; ya.x = g0[24]*vc[3] + g0[26]*vsn[3]; ya.y = g0[25]*vc[3] + g0[27]*vsn[3];
        v2f yb; yb.x = g0[28]*vc[3] + g0[30]*vsn[3]; yb.y = g0[29]*vc[3] + g0[31]*vsn[3];
        const v2f nya = nsw(ya), nyb = nsw(yb);
#pragma unroll
        for (int k = 7; k >= 0; --k) {
            const v2f h = sv[k >> 1];
            const v2f y  = (k & 1) ? yb  : ya;
            const v2f ny = (k & 1) ? nyb : nya;
            sv[k] = h.x * y + h.y * ny;
        }
    }
    {   // wire4: 8 -> 16
        v2f ya; ya.x = g0[32]*vc[4] + g0[34]*vsn[4]; ya.y = g0[33]*vc[4] + g0[35]*vsn[4];
        v2f yb; yb.x = g0[36]*vc[4] + g0[38]*vsn[4]; yb.y = g0[37]*vc[4] + g0[39]*vsn[4];
        const v2f nya = nsw(ya), nyb = nsw(yb);
#pragma unroll
        for (int k = 15; k >= 0; --k) {
            const v2f h = sv[k >> 1];
            const v2f y  = (k & 1) ? yb  : ya;
            const v2f ny = (k & 1) ? nyb : nya;
            sv[k] = h.x * y + h.y * ny;
        }
    }
    {   // wire5: 16 -> 32
        v2f ya; ya.x = g0[40]*vc[5] + g0[42]*vsn[5]; ya.y = g0[41]*vc[5] + g0[43]*vsn[5];
        v2f yb; yb.x = g0[44]*vc[5] + g0[46]*vsn[5]; yb.y = g0[45]*vc[5] + g0[47]*vsn[5];
        const v2f nya = nsw(ya), nyb = nsw(yb);
#pragma unroll
        for (int k = 31; k >= 0; --k) {
            const v2f h = sv[k >> 1];
            const v2f y  = (k & 1) ? yb  : ya;
            const v2f ny = (k & 1) ? nyb : nya;
            sv[k] = h.x * y + h.y * ny;
        }
    }

    // ---- layers act through composed maps; NO physical permutations ----
    if constexpr (USE_WS) {
        layer_apply<1>(sv, ws + 48, par);
        layer_apply<2>(sv, ws + 96, par);
    } else {
        compute_gates6(th_s + 18, gf);
        layer_apply<1>(sv, gf, par);
        compute_gates6(th_t, gf);
        layer_apply<2>(sv, gf, par);
    }

    // ---- <Z_w> readout through M3 ----
    float q[6] = {0.f, 0.f, 0.f, 0.f, 0.f, 0.f};
    readout_impl(sv, q, std::make_integer_sequence<int, 32>{});

    const float pm = par ? -1.f : 1.f;
    constexpr int invC = Minv(3, 32);   // parity contribution to M3^-1
#pragma unroll
    for (int w = 0; w < 6; ++w) {
        float tq = q[w];
        if ((invC >> (5 - w)) & 1) tq *= pm;
        q[w] = tq + swap1(tq);
    }

    // ---- head: out = q @ Wc^T + bc (split store across the lane pair) ----
    float o[5];
#pragma unroll
    for (int n = 0; n < 5; ++n) {
        float v = bc[n];
#pragma unroll
        for (int w = 0; w < 6; ++w) v = fmaf(q[w], Wc[n * 6 + w], v);
        o[n] = v;
    }
    float* orow = out + (long)row * 5;
    if (!par) { orow[0] = o[0]; orow[1] = o[1]; orow[2] = o[2]; }
    else      { orow[3] = o[3]; orow[4] = o[4]; }
}

extern "C" void kernel_launch(void* const* d_in, const int* in_sizes, int n_in,
                              void* d_out, int out_size, void* d_ws, size_t ws_size,
                              hipStream_t stream) {
    const float* x   = (const float*)d_in[0];
    const float* W1  = (const float*)d_in[1];
    const float* b1  = (const float*)d_in[2];
    const float* lng = (const float*)d_in[3];
    const float* lnb = (const float*)d_in[4];
    const float* W2  = (const float*)d_in[5];
    const float* b2  = (const float*)d_in[6];
    const float* ths = (const float*)d_in[7];
    const float* tht = (const float*)d_in[8];
    const float* Wc  = (const float*)d_in[9];
    const float* bc  = (const float*)d_in[10];
    float* out = (float*)d_out;
    float* ws  = (float*)d_ws;

    const int nrows = in_sizes[0] / 64;              // 131072
    const int nthreads = nrows * 2;                  // 2 lanes per row
    const int grid = (nthreads + 255) / 256;

    if (ws_size >= 668 * sizeof(float)) {
        setup_kernel<<<1, 384, 0, stream>>>(ths, tht, lng, lnb, W2, b2, b1, ws);
        qmaml_kernel<true><<<grid, 256, 0, stream>>>(x, W1, b1, lng, lnb, W2, b2,
                                                     ths, tht, Wc, bc, ws, out, nrows);
    } else {
        qmaml_kernel<false><<<grid, 256, 0, stream>>>(x, W1, b1, lng, lnb, W2, b2,
                                                      ths, tht, Wc, bc, nullptr, out, nrows);
    }
}

// Round 13
// 143.830 us; speedup vs baseline: 1.0230x; 1.0230x over previous
//
#include <hip/hip_runtime.h>
#include <utility>

#define NQ 6
#define DIM 64

typedef float v2f __attribute__((ext_vector_type(2)));

namespace {

// ---- compile-time ring permutation (CNOT ladder), matching _ring_perm ----
constexpr int ring_entry(int r, int i) {
    int idx = i;
    for (int w = NQ - 1; w >= 0; --w) {
        int c = w;
        int t = (w + r) % NQ;
        int cbit = (idx >> (NQ - 1 - c)) & 1;
        idx ^= cbit << (NQ - 1 - t);
    }
    return idx;
}

// Logical->physical composed map after L rings (all rings are GF(2)-linear).
constexpr int Mc(int L, int i) {
    if (L == 1) return ring_entry(1, i);
    if (L == 2) return ring_entry(1, ring_entry(2, i));
    if (L == 3) return ring_entry(1, ring_entry(2, ring_entry(1, i)));
    return i;
}

constexpr int Minv(int L, int p) {
    for (int i = 0; i < DIM; ++i) if (Mc(L, i) == p) return i;
    return -1;
}

} // namespace

// ---- 1-instr VALU lane swap (pairs 2r<->2r+1): DPP quad_perm [1,0,3,2] ----
__device__ __forceinline__ float swap1(float v) {
    return __int_as_float(__builtin_amdgcn_mov_dpp(__float_as_int(v), 0xB1, 0xF, 0xF, true));
}
__device__ __forceinline__ v2f swap1v(v2f v) {
    v2f r; r.x = swap1(v.x); r.y = swap1(v.y); return r;
}
// generic quad_perm DPP on a v2f (CTL: 0xB1 = lane^1, 0x4E = lane^2)
template<int CTL>
__device__ __forceinline__ v2f dppv(v2f v) {
    v2f r;
    r.x = __int_as_float(__builtin_amdgcn_mov_dpp(__float_as_int(v.x), CTL, 0xF, 0xF, true));
    r.y = __int_as_float(__builtin_amdgcn_mov_dpp(__float_as_int(v.y), CTL, 0xF, 0xF, true));
    return r;
}
// (-v.y, v.x): the i* twiddle -- folds into VOP3P op_sel/neg on pk_fma
__device__ __forceinline__ v2f nsw(v2f v) {
    v2f r; r.x = -v.y; r.y = v.x; return r;
}

// ===== gate application in the fixed physical frame via composed maps =====
// 2 lanes per row: lane par = t&1 holds physical slots p = par*32 + l, l in [0,32).
// state: v2f sv[l] = (re, im) of slot l. logical i = Minv(L, p).

template<int LY, int W, int d, int... Ls>
__device__ __forceinline__ void wire_inlane(v2f* sv,
        float A0r, float A0i, float B0r, float B0i,
        float A1r, float A1i, float B1r, float B1i,
        std::integer_sequence<int, Ls...>) {
    (([&] {
        if constexpr (Ls < (Ls ^ d)) {
            constexpr int la = Ls, lb = Ls ^ d;
            constexpr int ra = (Minv(LY, la) >> (5 - W)) & 1;
            constexpr int rb = (Minv(LY, lb) >> (5 - W)) & 1;
            const float cAar = ra ? A1r : A0r, cAai = ra ? A1i : A0i;
            const float cBar = ra ? B1r : B0r, cBai = ra ? B1i : B0i;
            const float cAbr = rb ? A1r : A0r, cAbi = rb ? A1i : A0i;
            const float cBbr = rb ? B1r : B0r, cBbi = rb ? B1i : B0i;
            const v2f ma = sv[la], mb = sv[lb];
            const v2f na = nsw(ma), nb = nsw(mb);
            sv[la] = cAar*ma + cAai*na + cBar*mb + cBai*nb;
            sv[lb] = cAbr*mb + cAbi*nb + cBbr*ma + cBbi*na;
        }
    }()), ...);
}

template<int LY, int W, int... Ls>
__device__ __forceinline__ void wire_cross0(v2f* sv,
        float A0r, float A0i, float B0r, float B0i,
        float A1r, float A1i, float B1r, float B1i,
        std::integer_sequence<int, Ls...>) {
    (([&] {
        constexpr int r = (Minv(LY, Ls) >> (5 - W)) & 1;
        const float cAr = r ? A1r : A0r, cAi = r ? A1i : A0i;
        const float cBr = r ? B1r : B0r, cBi = r ? B1i : B0i;
        const v2f m = sv[Ls];
        const v2f t = swap1v(m);          // partner lane, same slot (old value)
        sv[Ls] = cAr*m + cAi*nsw(m) + cBr*t + cBi*nsw(t);
    }()), ...);
}

template<int LY, int W, int d, int... Ls>
__device__ __forceinline__ void wire_crossd(v2f* sv,
        float A0r, float A0i, float B0r, float B0i,
        float A1r, float A1i, float B1r, float B1i,
        std::integer_sequence<int, Ls...>) {
    (([&] {
        if constexpr (Ls < (Ls ^ d)) {
            constexpr int la = Ls, lb = Ls ^ d;
            constexpr int ra = (Minv(LY, la) >> (5 - W)) & 1;
            constexpr int rb = (Minv(LY, lb) >> (5 - W)) & 1;
            const float cAar = ra ? A1r : A0r, cAai = ra ? A1i : A0i;
            const float cBar = ra ? B1r : B0r, cBai = ra ? B1i : B0i;
            const float cAbr = rb ? A1r : A0r, cAbi = rb ? A1i : A0i;
            const float cBbr = rb ? B1r : B0r, cBbi = rb ? B1i : B0i;
            const v2f ma = sv[la], mb = sv[lb];
            const v2f ta = swap1v(mb);    // partner lane old [lb]
            const v2f tb = swap1v(ma);    // partner lane old [la]
            sv[la] = cAar*ma + cAai*nsw(ma) + cBar*ta + cBai*nsw(ta);
            sv[lb] = cAbr*mb + cAbi*nsw(mb) + cBbr*tb + cBbi*nsw(tb);
        }
    }()), ...);
}

template<int LY, int W>
__device__ __forceinline__ void wire_apply(v2f* sv,
        const float* __restrict__ g, bool par) {
    constexpr int D = Mc(LY, 1 << (5 - W));     // physical pair offset (linear map)
    constexpr bool cross = (D >> 5) & 1;
    constexpr int d = D & 31;
    constexpr bool cpar = (Minv(LY, 32) >> (5 - W)) & 1;  // role flips with parity

    float A0r, A0i, B0r, B0i, A1r, A1i, B1r, B1i;
    if constexpr (cpar) {
        A0r = par ? g[6] : g[0];  A0i = par ? g[7] : g[1];
        B0r = par ? g[4] : g[2];  B0i = par ? g[5] : g[3];
        A1r = par ? g[0] : g[6];  A1i = par ? g[1] : g[7];
        B1r = par ? g[2] : g[4];  B1i = par ? g[3] : g[5];
    } else {
        A0r = g[0]; A0i = g[1]; B0r = g[2]; B0i = g[3];
        A1r = g[6]; A1i = g[7]; B1r = g[4]; B1i = g[5];
    }
    if constexpr (!cross) {
        wire_inlane<LY, W, d>(sv, A0r, A0i, B0r, B0i, A1r, A1i, B1r, B1i,
                              std::make_integer_sequence<int, 32>{});
    } else if constexpr (d == 0) {
        wire_cross0<LY, W>(sv, A0r, A0i, B0r, B0i, A1r, A1i, B1r, B1i,
                           std::make_integer_sequence<int, 32>{});
    } else {
        wire_crossd<LY, W, d>(sv, A0r, A0i, B0r, B0i, A1r, A1i, B1r, B1i,
                              std::make_integer_sequence<int, 32>{});
    }
}

template<int LY>
__device__ __forceinline__ void layer_apply(v2f* sv,
        const float* __restrict__ g, bool par) {
    wire_apply<LY, 0>(sv, g,      par);
    wire_apply<LY, 1>(sv, g + 8,  par);
    wire_apply<LY, 2>(sv, g + 16, par);
    wire_apply<LY, 3>(sv, g + 24, par);
    wire_apply<LY, 4>(sv, g + 32, par);
    wire_apply<LY, 5>(sv, g + 40, par);
}

// ---- readout: fold full M3 into constexpr signs + one parity flip ----
template<int... Ls>
__device__ __forceinline__ void readout_impl(const v2f* sv, float* q,
                                             std::integer_sequence<int, Ls...>) {
    (([&] {
        constexpr int iv = Minv(3, Ls);
        const float pb = fmaf(sv[Ls].x, sv[Ls].x, sv[Ls].y * sv[Ls].y);
        q[0] += ((iv >> 5) & 1) ? -pb : pb;
        q[1] += ((iv >> 4) & 1) ? -pb : pb;
        q[2] += ((iv >> 3) & 1) ? -pb : pb;
        q[3] += ((iv >> 2) & 1) ? -pb : pb;
        q[4] += ((iv >> 1) & 1) ? -pb : pb;
        q[5] += ( iv       & 1) ? -pb : pb;
    }()), ...);
}

// ---- per-thread gate computation (fallback path only) ----
__device__ __forceinline__ void compute_gates6(const float* __restrict__ th, float* g) {
#pragma unroll
    for (int w = 0; w < NQ; ++w) {
        const float phi = th[w*3+0], theta = th[w*3+1], omega = th[w*3+2];
        float s, c, sa, ca, sb, cb;
        __sincosf(0.5f * theta, &s, &c);
        __sincosf(0.5f * (phi + omega), &sa, &ca);
        __sincosf(0.5f * (phi - omega), &sb, &cb);
        g[w*8+0] =  ca * c;  g[w*8+1] = -sa * c;
        g[w*8+2] = -cb * s;  g[w*8+3] = -sb * s;
        g[w*8+4] =  cb * s;  g[w*8+5] = -sb * s;
        g[w*8+6] =  ca * c;  g[w*8+7] =  sa * c;
    }
}

// ---- setup: gates (18x8) + Gt[j][m] = ln_g[j]*W2[m][j] (64x6) + C1/C2 ----
// ws floats: [0,144) gates, [144,528) Gt (j*6+m), [528,534) C1, [534,540) C2+b2
__global__ void setup_kernel(const float* __restrict__ th_s, const float* __restrict__ th_t,
                             const float* __restrict__ ln_g, const float* __restrict__ ln_b,
                             const float* __restrict__ W2, const float* __restrict__ b2,
                             float* __restrict__ ws) {
    const int t = threadIdx.x;
    if (t < 18) {
        const int l = t / 6, w = t % 6;
        const float* th = (l < 2) ? (th_s + (l * 6 + w) * 3) : (th_t + w * 3);
        const float phi = th[0], theta = th[1], omega = th[2];
        float s, c, sa, ca, sb, cb;
        sincosf(0.5f * theta, &s, &c);
        sincosf(0.5f * (phi + omega), &sa, &ca);
        sincosf(0.5f * (phi - omega), &sb, &cb);
        float* g = ws + t * 8;
        g[0] =  ca * c;  g[1] = -sa * c;
        g[2] = -cb * s;  g[3] = -sb * s;
        g[4] =  cb * s;  g[5] = -sb * s;
        g[6] =  ca * c;  g[7] =  sa * c;
    }
    if (t < 384) {
        const int j = t / 6, m = t % 6;
        ws[144 + t] = ln_g[j] * W2[m * 64 + j];
    }
    if (t < 6) {
        float c1 = 0.f, c2 = 0.f;
        for (int j = 0; j < 64; ++j) {
            c1 += ln_g[j] * W2[t * 64 + j];
            c2 += ln_b[j] * W2[t * 64 + j];
        }
        ws[528 + t] = c1;
        ws[534 + t] = c2 + b2[t];
    }
}

template<bool USE_WS>
__global__ __launch_bounds__(256, 4)   // 128-VGPR budget: allocator fits naturally, no spill
void qmaml_kernel(
    const float* __restrict__ x,  const float* __restrict__ W1, const float* __restrict__ b1,
    const float* __restrict__ ln_g, const float* __restrict__ ln_b,
    const float* __restrict__ W2, const float* __restrict__ b2,
    const float* __restrict__ th_s, const float* __restrict__ th_t,
    const float* __restrict__ Wc, const float* __restrict__ bc,
    const float* __restrict__ ws, float* __restrict__ out, int nrows) {

    // ---- stage W1 into LDS (16 KB) ----
    __shared__ float4 wl[1024];
    {
        const float4* wg = (const float4*)W1;
        const int tid = threadIdx.x;
#pragma unroll
        for (int k = 0; k < 4; ++k) wl[tid + (k << 8)] = wg[tid + (k << 8)];
    }
    __syncthreads();

    const int t   = blockIdx.x * 256 + threadIdx.x;
    const int row = t >> 1;
    const bool par = t & 1;            // = logical wire-0 bit of my half-state
    if (row >= nrows) return;

    const int qi = t & 3;              // position within the lane QUAD (2 rows)
    const int rA = (t >> 2) << 1;      // quad's even row; odd row = rA+1

    // ---- load x QUARTERS for BOTH rows of my quad (Tr=2 blocking) ----
    // lane qi owns k in [16*qi, 16*qi+16) for rows rA and rA+1.
    v2f xA[8], xB[8];
    {
        const float4* xpA = (const float4*)(x + (long)rA * 64 + (qi << 4));
        const float4* xpB = (const float4*)(x + (long)(rA + 1) * 64 + (qi << 4));
#pragma unroll
        for (int k = 0; k < 4; ++k) {
            const float4 a = xpA[k];
            const float4 b = xpB[k];
            xA[2*k].x   = a.x; xA[2*k].y   = a.y;
            xA[2*k+1].x = a.z; xA[2*k+1].y = a.w;
            xB[2*k].x   = b.x; xB[2*k].y   = b.y;
            xB[2*k+1].x = b.z; xB[2*k+1].y = b.w;
        }
    }

    // ---- quad-blocked matvec: each lane reads a QUARTER W1 row per j ----
    // (4 ds_read_b128/j instead of 8 -- halves LDS instruction pressure),
    // FMAs it against both rows' x-quarters, reduces (pA,pB) packed with
    // 2 intra-quad DPP hops. All lanes run all 64 j; pair lanes end
    // bit-identical (no merges needed).
    v2f A2[3]; A2[0] = 0.f; A2[1] = 0.f; A2[2] = 0.f;
    float A[6]  = {0.f, 0.f, 0.f, 0.f, 0.f, 0.f};
    float C1[6] = {0.f, 0.f, 0.f, 0.f, 0.f, 0.f};
    float C2[6] = {0.f, 0.f, 0.f, 0.f, 0.f, 0.f};
    float s = 0.f, s2 = 0.f;

    const bool rowB = qi & 2;          // my row is the quad's odd row
#pragma unroll 2
    for (int j = 0; j < 64; ++j) {
        const float4* wr = &wl[j * 16 + (qi << 2)];
        v2f a0; a0 = 0.f;
        v2f a1; a1 = 0.f;
        v2f b0; b0 = 0.f;
        v2f b1v; b1v = 0.f;
#pragma unroll
        for (int k = 0; k < 4; ++k) {
            const float4 w4 = wr[k];
            v2f w0; w0.x = w4.x; w0.y = w4.y;
            v2f w1; w1.x = w4.z; w1.y = w4.w;
            a0  = w0 * xA[2*k]     + a0;
            a1  = w1 * xA[2*k + 1] + a1;
            b0  = w0 * xB[2*k]     + b0;
            b1v = w1 * xB[2*k + 1] + b1v;
        }
        const v2f vA = a0 + a1;
        const v2f vB = b0 + b1v;
        v2f P; P.x = vA.x + vA.y; P.y = vB.x + vB.y;
        P = P + dppv<0xB1>(P);         // quad xor 1
        P = P + dppv<0x4E>(P);         // quad xor 2: all 4 lanes = (totA, totB)
        const float tot = rowB ? P.y : P.x;
        if constexpr (USE_WS) {
            const float acc = fmaxf(tot + b1[j], 0.f);
            s += acc; s2 = fmaf(acc, acc, s2);
            const v2f* Gt2 = (const v2f*)(ws + 144 + j * 6);   // 6 floats, 8B-aligned
            A2[0] = acc * Gt2[0] + A2[0];
            A2[1] = acc * Gt2[1] + A2[1];
            A2[2] = acc * Gt2[2] + A2[2];
        } else {
            const float acc = fmaxf(tot + b1[j], 0.f);
            s += acc; s2 = fmaf(acc, acc, s2);
            const float gj = ln_g[j], bj = ln_b[j];
#pragma unroll
            for (int m = 0; m < 6; ++m) {
                const float w2 = W2[m * 64 + j];
                const float gw = gj * w2;
                A[m]  = fmaf(acc, gw, A[m]);
                C1[m] += gw;
                C2[m] = fmaf(bj, w2, C2[m]);
            }
        }
    }
    if constexpr (USE_WS) {
        A[0] = A2[0].x; A[1] = A2[0].y; A[2] = A2[1].x;
        A[3] = A2[1].y; A[4] = A2[2].x; A[5] = A2[2].y;
    }

    const float mu  = s  * (1.f / 64.f);
    const float var = s2 * (1.f / 64.f) - mu * mu;
    const float inv = rsqrtf(var + 1e-5f);

    // ---- z = tanh(...), per-wire (cos, sin) ----
    float vc[6], vsn[6];
#pragma unroll
    for (int m = 0; m < 6; ++m) {
        float c1v, c2v;
        if constexpr (USE_WS) { c1v = ws[528 + m]; c2v = ws[534 + m]; }
        else                  { c1v = C1[m];       c2v = C2[m] + b2[m]; }
        const float zp = inv * (A[m] - mu * c1v) + c2v;
        const float e  = __expf(2.f * zp);
        const float z  = 1.f - 2.f / (e + 1.f);
        const float half = 1.57079632679f * z;
        vsn[m] = __sinf(half);
        vc[m]  = __cosf(half);
    }

    float gf[48];
    const float* g0;
    if constexpr (USE_WS) g0 = ws;      // wave-uniform -> SGPR s_loads
    else { compute_gates6(th_s, gf); g0 = gf; }

    // ---- build my 32 amps IN PLACE as packed complex ----
    v2f sv[32];
    {
        const float a0r = par ? (g0[4]*vc[0] + g0[6]*vsn[0]) : (g0[0]*vc[0] + g0[2]*vsn[0]);
        const float a0i = par ? (g0[5]*vc[0] + g0[7]*vsn[0]) : (g0[1]*vc[0] + g0[3]*vsn[0]);
        v2f ga1; ga1.x = g0[8]  * vc[1] + g0[10] * vsn[1];
                 ga1.y = g0[9]  * vc[1] + g0[11] * vsn[1];
        v2f gb1; gb1.x = g0[12] * vc[1] + g0[14] * vsn[1];
                 gb1.y = g0[13] * vc[1] + g0[15] * vsn[1];
        sv[0] = a0r * ga1 + a0i * nsw(ga1);
        sv[1] = a0r * gb1 + a0i * nsw(gb1);
    }
    {   // wire2: 2 -> 4
        v2f ya; ya.x = g0[16]*vc[2] + g0[18]*vsn[2]; ya.y = g0[17]*vc[2] + g0[19]*vsn[2];
        v2f yb; yb.x = g0[20]*vc[2] + g0[22]*vsn[2]; yb.y = g0[21]*vc[2] + g0[23]*vsn[2];
        const v2f nya = nsw(ya), nyb = nsw(yb);
#pragma unroll
        for (int k = 3; k >= 0; --k) {
            const v2f h = sv[k >> 1];
            const v2f y  = (k & 1) ? yb  : ya;
            const v2f ny = (k & 1) ? nyb : nya;
            sv[k] = h.x * y + h.y * ny;
        }
    }
    {   // wire3: 4 -> 8
        v2f ya; ya.x = g0[24]*vc[3] + g0[26]*vsn[3]; ya.y = g0[25]*vc[3] + g0[27]*vsn[3];
        v2f yb; yb.x = g0[28]*vc[3] + g0[30]*vsn[3]; yb.y = g0[29]*vc[3] + g0[31]*vsn[3];
        const v2f nya = nsw(ya), nyb = nsw(yb);
#pragma unroll
        for (int k = 7; k >= 0; --k) {
            const v2f h = sv[k >> 1];
            const v2f y  = (k & 1) ? yb  : ya;
            const v2f ny = (k & 1) ? nyb : nya;
            sv[k] = h.x * y + h.y * ny;
        }
    }
    {   // wire4: 8 -> 16
        v2f ya; ya.x = g0[32]*vc[4] + g0[34]*vsn[4]; ya.y = g0[33]*vc[4] + g0[35]*vsn[4];
        v2f yb; yb.x = g0[36]*vc[4] + g0[38]*vsn[4]; yb.y = g0[37]*vc[4] + g0[39]*vsn[4];
        const v2f nya = nsw(ya), nyb = nsw(yb);
#pragma unroll
        for (int k = 15; k >= 0; --k) {
            const v2f h = sv[k >> 1];
            const v2f y  = (k & 1) ? yb  : ya;
            const v2f ny = (k & 1) ? nyb : nya;
            sv[k] = h.x * y + h.y * ny;
        }
    }
    {   // wire5: 16 -> 32
        v2f ya; ya.x = g0[40]*vc[5] + g0[42]*vsn[5]; ya.y = g0[41]*vc[5] + g0[43]*vsn[5];
        v2f yb; yb.x = g0[44]*vc[5] + g0[46]*vsn[5]; yb.y = g0[45]*vc[5] + g0[47]*vsn[5];
        const v2f nya = nsw(ya), nyb = nsw(yb);
#pragma unroll
        for (int k = 31; k >= 0; --k) {
            const v2f h = sv[k >> 1];
            const v2f y  = (k & 1) ? yb  : ya;
            const v2f ny = (k & 1) ? nyb : nya;
            sv[k] = h.x * y + h.y * ny;
        }
    }

    // ---- layers act through composed maps; NO physical permutations ----
    if constexpr (USE_WS) {
        layer_apply<1>(sv, ws + 48, par);
        layer_apply<2>(sv, ws + 96, par);
    } else {
        compute_gates6(th_s + 18, gf);
        layer_apply<1>(sv, gf, par);
        compute_gates6(th_t, gf);
        layer_apply<2>(sv, gf, par);
    }

    // ---- <Z_w> readout through M3 ----
    float q[6] = {0.f, 0.f, 0.f, 0.f, 0.f, 0.f};
    readout_impl(sv, q, std::make_integer_sequence<int, 32>{});

    const float pm = par ? -1.f : 1.f;
    constexpr int invC = Minv(3, 32);   // parity contribution to M3^-1
#pragma unroll
    for (int w = 0; w < 6; ++w) {
        float tq = q[w];
        if ((invC >> (5 - w)) & 1) tq *= pm;
        q[w] = tq + swap1(tq);
    }

    // ---- head: out = q @ Wc^T + bc (split store across the lane pair) ----
    float o[5];
#pragma unroll
    for (int n = 0; n < 5; ++n) {
        float v = bc[n];
#pragma unroll
        for (int w = 0; w < 6; ++w) v = fmaf(q[w], Wc[n * 6 + w], v);
        o[n] = v;
    }
    float* orow = out + (long)row * 5;
    if (!par) { orow[0] = o[0]; orow[1] = o[1]; orow[2] = o[2]; }
    else      { orow[3] = o[3]; orow[4] = o[4]; }
}

extern "C" void kernel_launch(void* const* d_in, const int* in_sizes, int n_in,
                              void* d_out, int out_size, void* d_ws, size_t ws_size,
                              hipStream_t stream) {
    const float* x   = (const float*)d_in[0];
    const float* W1  = (const float*)d_in[1];
    const float* b1  = (const float*)d_in[2];
    const float* lng = (const float*)d_in[3];
    const float* lnb = (const float*)d_in[4];
    const float* W2  = (const float*)d_in[5];
    const float* b2  = (const float*)d_in[6];
    const float* ths = (const float*)d_in[7];
    const float* tht = (const float*)d_in[8];
    const float* Wc  = (const float*)d_in[9];
    const float* bc  = (const float*)d_in[10];
    float* out = (float*)d_out;
    float* ws  = (float*)d_ws;

    const int nrows = in_sizes[0] / 64;              // 131072
    const int nthreads = nrows * 2;                  // 2 lanes per row
    const int grid = (nthreads + 255) / 256;

    if (ws_size >= 540 * sizeof(float)) {
        setup_kernel<<<1, 384, 0, stream>>>(ths, tht, lng, lnb, W2, b2, ws);
        qmaml_kernel<true><<<grid, 256, 0, stream>>>(x, W1, b1, lng, lnb, W2, b2,
                                                     ths, tht, Wc, bc, ws, out, nrows);
    } else {
        qmaml_kernel<false><<<grid, 256, 0, stream>>>(x, W1, b1, lng, lnb, W2, b2,
                                                      ths, tht, Wc, bc, nullptr, out, nrows);
    }
}

// Round 14
// 140.971 us; speedup vs baseline: 1.0437x; 1.0203x over previous
//
#include <hip/hip_runtime.h>
#include <utility>

#define NQ 6
#define DIM 64

typedef float v2f __attribute__((ext_vector_type(2)));

namespace {

// ---- compile-time ring permutation (CNOT ladder), matching _ring_perm ----
constexpr int ring_entry(int r, int i) {
    int idx = i;
    for (int w = NQ - 1; w >= 0; --w) {
        int c = w;
        int t = (w + r) % NQ;
        int cbit = (idx >> (NQ - 1 - c)) & 1;
        idx ^= cbit << (NQ - 1 - t);
    }
    return idx;
}

// Logical->physical composed map after L rings (all rings are GF(2)-linear).
constexpr int Mc(int L, int i) {
    if (L == 1) return ring_entry(1, i);
    if (L == 2) return ring_entry(1, ring_entry(2, i));
    if (L == 3) return ring_entry(1, ring_entry(2, ring_entry(1, i)));
    return i;
}

constexpr int Minv(int L, int p) {
    for (int i = 0; i < DIM; ++i) if (Mc(L, i) == p) return i;
    return -1;
}

} // namespace

// ---- 1-instr VALU lane swap (pairs 2r<->2r+1): DPP quad_perm [1,0,3,2] ----
__device__ __forceinline__ float swap1(float v) {
    return __int_as_float(__builtin_amdgcn_mov_dpp(__float_as_int(v), 0xB1, 0xF, 0xF, true));
}
__device__ __forceinline__ v2f swap1v(v2f v) {
    v2f r; r.x = swap1(v.x); r.y = swap1(v.y); return r;
}
// generic quad_perm DPP on a v2f (CTL: 0xB1 = lane^1, 0x4E = lane^2)
template<int CTL>
__device__ __forceinline__ v2f dppv(v2f v) {
    v2f r;
    r.x = __int_as_float(__builtin_amdgcn_mov_dpp(__float_as_int(v.x), CTL, 0xF, 0xF, true));
    r.y = __int_as_float(__builtin_amdgcn_mov_dpp(__float_as_int(v.y), CTL, 0xF, 0xF, true));
    return r;
}
// (-v.y, v.x): the i* twiddle -- folds into VOP3P op_sel/neg on pk_fma
__device__ __forceinline__ v2f nsw(v2f v) {
    v2f r; r.x = -v.y; r.y = v.x; return r;
}

// ===== gate application in the fixed physical frame via composed maps =====
// 2 lanes per row: lane par = t&1 holds physical slots p = par*32 + l, l in [0,32).
// state: v2f sv[l] = (re, im) of slot l. logical i = Minv(L, p).

template<int LY, int W, int d, int... Ls>
__device__ __forceinline__ void wire_inlane(v2f* sv,
        float A0r, float A0i, float B0r, float B0i,
        float A1r, float A1i, float B1r, float B1i,
        std::integer_sequence<int, Ls...>) {
    (([&] {
        if constexpr (Ls < (Ls ^ d)) {
            constexpr int la = Ls, lb = Ls ^ d;
            constexpr int ra = (Minv(LY, la) >> (5 - W)) & 1;
            constexpr int rb = (Minv(LY, lb) >> (5 - W)) & 1;
            const float cAar = ra ? A1r : A0r, cAai = ra ? A1i : A0i;
            const float cBar = ra ? B1r : B0r, cBai = ra ? B1i : B0i;
            const float cAbr = rb ? A1r : A0r, cAbi = rb ? A1i : A0i;
            const float cBbr = rb ? B1r : B0r, cBbi = rb ? B1i : B0i;
            const v2f ma = sv[la], mb = sv[lb];
            const v2f na = nsw(ma), nb = nsw(mb);
            sv[la] = cAar*ma + cAai*na + cBar*mb + cBai*nb;
            sv[lb] = cAbr*mb + cAbi*nb + cBbr*ma + cBbi*na;
        }
    }()), ...);
}

template<int LY, int W, int... Ls>
__device__ __forceinline__ void wire_cross0(v2f* sv,
        float A0r, float A0i, float B0r, float B0i,
        float A1r, float A1i, float B1r, float B1i,
        std::integer_sequence<int, Ls...>) {
    (([&] {
        constexpr int r = (Minv(LY, Ls) >> (5 - W)) & 1;
        const float cAr = r ? A1r : A0r, cAi = r ? A1i : A0i;
        const float cBr = r ? B1r : B0r, cBi = r ? B1i : B0i;
        const v2f m = sv[Ls];
        const v2f t = swap1v(m);          // partner lane, same slot (old value)
        sv[Ls] = cAr*m + cAi*nsw(m) + cBr*t + cBi*nsw(t);
    }()), ...);
}

template<int LY, int W, int d, int... Ls>
__device__ __forceinline__ void wire_crossd(v2f* sv,
        float A0r, float A0i, float B0r, float B0i,
        float A1r, float A1i, float B1r, float B1i,
        std::integer_sequence<int, Ls...>) {
    (([&] {
        if constexpr (Ls < (Ls ^ d)) {
            constexpr int la = Ls, lb = Ls ^ d;
            constexpr int ra = (Minv(LY, la) >> (5 - W)) & 1;
            constexpr int rb = (Minv(LY, lb) >> (5 - W)) & 1;
            const float cAar = ra ? A1r : A0r, cAai = ra ? A1i : A0i;
            const float cBar = ra ? B1r : B0r, cBai = ra ? B1i : B0i;
            const float cAbr = rb ? A1r : A0r, cAbi = rb ? A1i : A0i;
            const float cBbr = rb ? B1r : B0r, cBbi = rb ? B1i : B0i;
            const v2f ma = sv[la], mb = sv[lb];
            const v2f ta = swap1v(mb);    // partner lane old [lb]
            const v2f tb = swap1v(ma);    // partner lane old [la]
            sv[la] = cAar*ma + cAai*nsw(ma) + cBar*ta + cBai*nsw(ta);
            sv[lb] = cAbr*mb + cAbi*nsw(mb) + cBbr*tb + cBbi*nsw(tb);
        }
    }()), ...);
}

template<int LY, int W>
__device__ __forceinline__ void wire_apply(v2f* sv,
        const float* __restrict__ g, bool par) {
    constexpr int D = Mc(LY, 1 << (5 - W));     // physical pair offset (linear map)
    constexpr bool cross = (D >> 5) & 1;
    constexpr int d = D & 31;
    constexpr bool cpar = (Minv(LY, 32) >> (5 - W)) & 1;  // role flips with parity

    float A0r, A0i, B0r, B0i, A1r, A1i, B1r, B1i;
    if constexpr (cpar) {
        A0r = par ? g[6] : g[0];  A0i = par ? g[7] : g[1];
        B0r = par ? g[4] : g[2];  B0i = par ? g[5] : g[3];
        A1r = par ? g[0] : g[6];  A1i = par ? g[1] : g[7];
        B1r = par ? g[2] : g[4];  B1i = par ? g[3] : g[5];
    } else {
        A0r = g[0]; A0i = g[1]; B0r = g[2]; B0i = g[3];
        A1r = g[6]; A1i = g[7]; B1r = g[4]; B1i = g[5];
    }
    if constexpr (!cross) {
        wire_inlane<LY, W, d>(sv, A0r, A0i, B0r, B0i, A1r, A1i, B1r, B1i,
                              std::make_integer_sequence<int, 32>{});
    } else if constexpr (d == 0) {
        wire_cross0<LY, W>(sv, A0r, A0i, B0r, B0i, A1r, A1i, B1r, B1i,
                           std::make_integer_sequence<int, 32>{});
    } else {
        wire_crossd<LY, W, d>(sv, A0r, A0i, B0r, B0i, A1r, A1i, B1r, B1i,
                              std::make_integer_sequence<int, 32>{});
    }
}

template<int LY>
__device__ __forceinline__ void layer_apply(v2f* sv,
        const float* __restrict__ g, bool par) {
    wire_apply<LY, 0>(sv, g,      par);
    wire_apply<LY, 1>(sv, g + 8,  par);
    wire_apply<LY, 2>(sv, g + 16, par);
    wire_apply<LY, 3>(sv, g + 24, par);
    wire_apply<LY, 4>(sv, g + 32, par);
    wire_apply<LY, 5>(sv, g + 40, par);
}

// ---- readout: fold full M3 into constexpr signs + one parity flip ----
template<int... Ls>
__device__ __forceinline__ void readout_impl(const v2f* sv, float* q,
                                             std::integer_sequence<int, Ls...>) {
    (([&] {
        constexpr int iv = Minv(3, Ls);
        const float pb = fmaf(sv[Ls].x, sv[Ls].x, sv[Ls].y * sv[Ls].y);
        q[0] += ((iv >> 5) & 1) ? -pb : pb;
        q[1] += ((iv >> 4) & 1) ? -pb : pb;
        q[2] += ((iv >> 3) & 1) ? -pb : pb;
        q[3] += ((iv >> 2) & 1) ? -pb : pb;
        q[4] += ((iv >> 1) & 1) ? -pb : pb;
        q[5] += ( iv       & 1) ? -pb : pb;
    }()), ...);
}

// ---- per-thread gate computation (fallback path only) ----
__device__ __forceinline__ void compute_gates6(const float* __restrict__ th, float* g) {
#pragma unroll
    for (int w = 0; w < NQ; ++w) {
        const float phi = th[w*3+0], theta = th[w*3+1], omega = th[w*3+2];
        float s, c, sa, ca, sb, cb;
        __sincosf(0.5f * theta, &s, &c);
        __sincosf(0.5f * (phi + omega), &sa, &ca);
        __sincosf(0.5f * (phi - omega), &sb, &cb);
        g[w*8+0] =  ca * c;  g[w*8+1] = -sa * c;
        g[w*8+2] = -cb * s;  g[w*8+3] = -sb * s;
        g[w*8+4] =  cb * s;  g[w*8+5] = -sb * s;
        g[w*8+6] =  ca * c;  g[w*8+7] =  sa * c;
    }
}

// ---- setup: gates (18x8) + Gt[j][m] = ln_g[j]*W2[m][j] (64x6) + C1/C2 ----
// ws floats: [0,144) gates, [144,528) Gt (j*6+m), [528,534) C1, [534,540) C2+b2
__global__ void setup_kernel(const float* __restrict__ th_s, const float* __restrict__ th_t,
                             const float* __restrict__ ln_g, const float* __restrict__ ln_b,
                             const float* __restrict__ W2, const float* __restrict__ b2,
                             float* __restrict__ ws) {
    const int t = threadIdx.x;
    if (t < 18) {
        const int l = t / 6, w = t % 6;
        const float* th = (l < 2) ? (th_s + (l * 6 + w) * 3) : (th_t + w * 3);
        const float phi = th[0], theta = th[1], omega = th[2];
        float s, c, sa, ca, sb, cb;
        sincosf(0.5f * theta, &s, &c);
        sincosf(0.5f * (phi + omega), &sa, &ca);
        sincosf(0.5f * (phi - omega), &sb, &cb);
        float* g = ws + t * 8;
        g[0] =  ca * c;  g[1] = -sa * c;
        g[2] = -cb * s;  g[3] = -sb * s;
        g[4] =  cb * s;  g[5] = -sb * s;
        g[6] =  ca * c;  g[7] =  sa * c;
    }
    if (t < 384) {
        const int j = t / 6, m = t % 6;
        ws[144 + t] = ln_g[j] * W2[m * 64 + j];
    }
    if (t < 6) {
        float c1 = 0.f, c2 = 0.f;
        for (int j = 0; j < 64; ++j) {
            c1 += ln_g[j] * W2[t * 64 + j];
            c2 += ln_b[j] * W2[t * 64 + j];
        }
        ws[528 + t] = c1;
        ws[534 + t] = c2 + b2[t];
    }
}

template<bool USE_WS>
__global__ __launch_bounds__(256, 4)   // 128-VGPR budget: allocator fits naturally, no spill
void qmaml_kernel(
    const float* __restrict__ x,  const float* __restrict__ W1, const float* __restrict__ b1,
    const float* __restrict__ ln_g, const float* __restrict__ ln_b,
    const float* __restrict__ W2, const float* __restrict__ b2,
    const float* __restrict__ th_s, const float* __restrict__ th_t,
    const float* __restrict__ Wc, const float* __restrict__ bc,
    const float* __restrict__ ws, float* __restrict__ out, int nrows) {

    // ---- stage W1 into LDS (16 KB) ----
    __shared__ float4 wl[1024];
    {
        const float4* wg = (const float4*)W1;
        const int tid = threadIdx.x;
#pragma unroll
        for (int k = 0; k < 4; ++k) wl[tid + (k << 8)] = wg[tid + (k << 8)];
    }
    __syncthreads();

    const int t   = blockIdx.x * 256 + threadIdx.x;
    const int row = t >> 1;
    const bool par = t & 1;            // = logical wire-0 bit of my half-state
    if (row >= nrows) return;

    const int qi = t & 3;              // position within the lane QUAD (2 rows)
    const int rA = (t >> 2) << 1;      // quad's even row; odd row = rA+1

    // ---- load x QUARTERS for BOTH rows of my quad (Tr=2 blocking) ----
    v2f xA[8], xB[8];
    {
        const float4* xpA = (const float4*)(x + (long)rA * 64 + (qi << 4));
        const float4* xpB = (const float4*)(x + (long)(rA + 1) * 64 + (qi << 4));
#pragma unroll
        for (int k = 0; k < 4; ++k) {
            const float4 a = xpA[k];
            const float4 b = xpB[k];
            xA[2*k].x   = a.x; xA[2*k].y   = a.y;
            xA[2*k+1].x = a.z; xA[2*k+1].y = a.w;
            xB[2*k].x   = b.x; xB[2*k].y   = b.y;
            xB[2*k+1].x = b.z; xB[2*k+1].y = b.w;
        }
    }

    // ---- quad-blocked matvec, SOFTWARE-PIPELINED (lookahead-1 reg dbuf) ----
    // Each j's 4 ds_read_b128 are issued one j ahead, so LDS latency hides
    // under the previous j's pk-FMA block. Tails processed per j-PAIR with
    // packed (pk) relu/stats.
    v2f A2[3]; A2[0] = 0.f; A2[1] = 0.f; A2[2] = 0.f;
    v2f sV;  sV  = 0.f;
    v2f s2V; s2V = 0.f;
    float A[6]  = {0.f, 0.f, 0.f, 0.f, 0.f, 0.f};
    float C1[6] = {0.f, 0.f, 0.f, 0.f, 0.f, 0.f};
    float C2[6] = {0.f, 0.f, 0.f, 0.f, 0.f, 0.f};
    float s = 0.f, s2 = 0.f;

    const bool rowB = qi & 2;          // my row is the quad's odd row
    const int  qoff = qi << 2;

    float4 w0[4], w1[4];
#pragma unroll
    for (int k = 0; k < 4; ++k) w0[k] = wl[qoff + k];       // j = 0 preload

    for (int j = 0; j < 64; j += 2) {
        // prefetch j+1 into w1
        {
            const float4* wrn = &wl[(j + 1) * 16 + qoff];
#pragma unroll
            for (int k = 0; k < 4; ++k) w1[k] = wrn[k];
        }
        // compute j with w0
        float totA;
        {
            v2f a0; a0 = 0.f; v2f a1; a1 = 0.f;
            v2f b0; b0 = 0.f; v2f b1v; b1v = 0.f;
#pragma unroll
            for (int k = 0; k < 4; ++k) {
                const float4 w4 = w0[k];
                v2f wlo; wlo.x = w4.x; wlo.y = w4.y;
                v2f whi; whi.x = w4.z; whi.y = w4.w;
                a0  = wlo * xA[2*k]     + a0;
                a1  = whi * xA[2*k + 1] + a1;
                b0  = wlo * xB[2*k]     + b0;
                b1v = whi * xB[2*k + 1] + b1v;
            }
            const v2f vA = a0 + a1, vB = b0 + b1v;
            v2f P; P.x = vA.x + vA.y; P.y = vB.x + vB.y;
            P = P + dppv<0xB1>(P);
            P = P + dppv<0x4E>(P);
            totA = rowB ? P.y : P.x;
        }
        // prefetch j+2 into w0 (wraps harmlessly on the final pair)
        {
            const float4* wr2 = &wl[((j + 2) & 63) * 16 + qoff];
#pragma unroll
            for (int k = 0; k < 4; ++k) w0[k] = wr2[k];
        }
        // compute j+1 with w1
        float totB_;
        {
            v2f a0; a0 = 0.f; v2f a1; a1 = 0.f;
            v2f b0; b0 = 0.f; v2f b1v; b1v = 0.f;
#pragma unroll
            for (int k = 0; k < 4; ++k) {
                const float4 w4 = w1[k];
                v2f wlo; wlo.x = w4.x; wlo.y = w4.y;
                v2f whi; whi.x = w4.z; whi.y = w4.w;
                a0  = wlo * xA[2*k]     + a0;
                a1  = whi * xA[2*k + 1] + a1;
                b0  = wlo * xB[2*k]     + b0;
                b1v = whi * xB[2*k + 1] + b1v;
            }
            const v2f vA = a0 + a1, vB = b0 + b1v;
            v2f P; P.x = vA.x + vA.y; P.y = vB.x + vB.y;
            P = P + dppv<0xB1>(P);
            P = P + dppv<0x4E>(P);
            totB_ = rowB ? P.y : P.x;
        }
        // paired tail for (j, j+1)
        if constexpr (USE_WS) {
            v2f t2; t2.x = totA; t2.y = totB_;
            const v2f b12 = *(const v2f*)(b1 + j);    // 8B-aligned (j even)
            const v2f sum = t2 + b12;
            v2f acc2; acc2.x = fmaxf(sum.x, 0.f); acc2.y = fmaxf(sum.y, 0.f);
            sV  = sV + acc2;
            s2V = acc2 * acc2 + s2V;
            const v2f* GtA = (const v2f*)(ws + 144 + j * 6);
            const v2f* GtB = (const v2f*)(ws + 144 + j * 6 + 6);
            A2[0] = acc2.x * GtA[0] + A2[0];
            A2[1] = acc2.x * GtA[1] + A2[1];
            A2[2] = acc2.x * GtA[2] + A2[2];
            A2[0] = acc2.y * GtB[0] + A2[0];
            A2[1] = acc2.y * GtB[1] + A2[1];
            A2[2] = acc2.y * GtB[2] + A2[2];
        } else {
            const float accA = fmaxf(totA + b1[j], 0.f);
            s += accA; s2 = fmaf(accA, accA, s2);
            {
                const float gj = ln_g[j], bj = ln_b[j];
#pragma unroll
                for (int m = 0; m < 6; ++m) {
                    const float w2 = W2[m * 64 + j];
                    const float gw = gj * w2;
                    A[m]  = fmaf(accA, gw, A[m]);
                    C1[m] += gw;
                    C2[m] = fmaf(bj, w2, C2[m]);
                }
            }
            const float accB = fmaxf(totB_ + b1[j + 1], 0.f);
            s += accB; s2 = fmaf(accB, accB, s2);
            {
                const float gj = ln_g[j + 1], bj = ln_b[j + 1];
#pragma unroll
                for (int m = 0; m < 6; ++m) {
                    const float w2 = W2[m * 64 + j + 1];
                    const float gw = gj * w2;
                    A[m]  = fmaf(accB, gw, A[m]);
                    C1[m] += gw;
                    C2[m] = fmaf(bj, w2, C2[m]);
                }
            }
        }
    }
    if constexpr (USE_WS) {
        s  = sV.x  + sV.y;
        s2 = s2V.x + s2V.y;
        A[0] = A2[0].x; A[1] = A2[0].y; A[2] = A2[1].x;
        A[3] = A2[1].y; A[4] = A2[2].x; A[5] = A2[2].y;
    }

    const float mu  = s  * (1.f / 64.f);
    const float var = s2 * (1.f / 64.f) - mu * mu;
    const float inv = rsqrtf(var + 1e-5f);

    // ---- z = tanh(...), per-wire (cos, sin) ----
    float vc[6], vsn[6];
#pragma unroll
    for (int m = 0; m < 6; ++m) {
        float c1v, c2v;
        if constexpr (USE_WS) { c1v = ws[528 + m]; c2v = ws[534 + m]; }
        else                  { c1v = C1[m];       c2v = C2[m] + b2[m]; }
        const float zp = inv * (A[m] - mu * c1v) + c2v;
        const float e  = __expf(2.f * zp);
        const float z  = 1.f - 2.f / (e + 1.f);
        const float half = 1.57079632679f * z;
        vsn[m] = __sinf(half);
        vc[m]  = __cosf(half);
    }

    float gf[48];
    const float* g0;
    if constexpr (USE_WS) g0 = ws;      // wave-uniform -> SGPR s_loads
    else { compute_gates6(th_s, gf); g0 = gf; }

    // ---- build my 32 amps IN PLACE as packed complex ----
    v2f sv[32];
    {
        const float a0r = par ? (g0[4]*vc[0] + g0[6]*vsn[0]) : (g0[0]*vc[0] + g0[2]*vsn[0]);
        const float a0i = par ? (g0[5]*vc[0] + g0[7]*vsn[0]) : (g0[1]*vc[0] + g0[3]*vsn[0]);
        v2f ga1; ga1.x = g0[8]  * vc[1] + g0[10] * vsn[1];
                 ga1.y = g0[9]  * vc[1] + g0[11] * vsn[1];
        v2f gb1; gb1.x = g0[12] * vc[1] + g0[14] * vsn[1];
                 gb1.y = g0[13] * vc[1] + g0[15] * vsn[1];
        sv[0] = a0r * ga1 + a0i * nsw(ga1);
        sv[1] = a0r * gb1 + a0i * nsw(gb1);
    }
    {   // wire2: 2 -> 4
        v2f ya; ya.x = g0[16]*vc[2] + g0[18]*vsn[2]; ya.y = g0[17]*vc[2] + g0[19]*vsn[2];
        v2f yb; yb.x = g0[20]*vc[2] + g0[22]*vsn[2]; yb.y = g0[21]*vc[2] + g0[23]*vsn[2];
        const v2f nya = nsw(ya), nyb = nsw(yb);
#pragma unroll
        for (int k = 3; k >= 0; --k) {
            const v2f h = sv[k >> 1];
            const v2f y  = (k & 1) ? yb  : ya;
            const v2f ny = (k & 1) ? nyb : nya;
            sv[k] = h.x * y + h.y * ny;
        }
    }
    {   // wire3: 4 -> 8
        v2f ya; ya.x = g0[24]*vc[3] + g0[26]*vsn[3]; ya.y = g0[25]*vc[3] + g0[27]*vsn[3];
        v2f yb; yb.x = g0[28]*vc[3] + g0[30]*vsn[3]; yb.y = g0[29]*vc[3] + g0[31]*vsn[3];
        const v2f nya = nsw(ya), nyb = nsw(yb);
#pragma unroll
        for (int k = 7; k >= 0; --k) {
            const v2f h = sv[k >> 1];
            const v2f y  = (k & 1) ? yb  : ya;
            const v2f ny = (k & 1) ? nyb : nya;
            sv[k] = h.x * y + h.y * ny;
        }
    }
    {   // wire4: 8 -> 16
        v2f ya; ya.x = g0[32]*vc[4] + g0[34]*vsn[4]; ya.y = g0[33]*vc[4] + g0[35]*vsn[4];
        v2f yb; yb.x = g0[36]*vc[4] + g0[38]*vsn[4]; yb.y = g0[37]*vc[4] + g0[39]*vsn[4];
        const v2f nya = nsw(ya), nyb = nsw(yb);
#pragma unroll
        for (int k = 15; k >= 0; --k) {
            const v2f h = sv[k >> 1];
            const v2f y  = (k & 1) ? yb  : ya;
            const v2f ny = (k & 1) ? nyb : nya;
            sv[k] = h.x * y + h.y * ny;
        }
    }
    {   // wire5: 16 -> 32
        v2f ya; ya.x = g0[40]*vc[5] + g0[42]*vsn[5]; ya.y = g0[41]*vc[5] + g0[43]*vsn[5];
        v2f yb; yb.x = g0[44]*vc[5] + g0[46]*vsn[5]; yb.y = g0[45]*vc[5] + g0[47]*vsn[5];
        const v2f nya = nsw(ya), nyb = nsw(yb);
#pragma unroll
        for (int k = 31; k >= 0; --k) {
            const v2f h = sv[k >> 1];
            const v2f y  = (k & 1) ? yb  : ya;
            const v2f ny = (k & 1) ? nyb : nya;
            sv[k] = h.x * y + h.y * ny;
        }
    }

    // ---- layers act through composed maps; NO physical permutations ----
    if constexpr (USE_WS) {
        layer_apply<1>(sv, ws + 48, par);
        layer_apply<2>(sv, ws + 96, par);
    } else {
        compute_gates6(th_s + 18, gf);
        layer_apply<1>(sv, gf, par);
        compute_gates6(th_t, gf);
        layer_apply<2>(sv, gf, par);
    }

    // ---- <Z_w> readout through M3 ----
    float q[6] = {0.f, 0.f, 0.f, 0.f, 0.f, 0.f};
    readout_impl(sv, q, std::make_integer_sequence<int, 32>{});

    const float pm = par ? -1.f : 1.f;
    constexpr int invC = Minv(3, 32);   // parity contribution to M3^-1
#pragma unroll
    for (int w = 0; w < 6; ++w) {
        float tq = q[w];
        if ((invC >> (5 - w)) & 1) tq *= pm;
        q[w] = tq + swap1(tq);
    }

    // ---- head: out = q @ Wc^T + bc (split store across the lane pair) ----
    float o[5];
#pragma unroll
    for (int n = 0; n < 5; ++n) {
        float v = bc[n];
#pragma unroll
        for (int w = 0; w < 6; ++w) v = fmaf(q[w], Wc[n * 6 + w], v);
        o[n] = v;
    }
    float* orow = out + (long)row * 5;
    if (!par) { orow[0] = o[0]; orow[1] = o[1]; orow[2] = o[2]; }
    else      { orow[3] = o[3]; orow[4] = o[4]; }
}

extern "C" void kernel_launch(void* const* d_in, const int* in_sizes, int n_in,
                              void* d_out, int out_size, void* d_ws, size_t ws_size,
                              hipStream_t stream) {
    const float* x   = (const float*)d_in[0];
    const float* W1  = (const float*)d_in[1];
    const float* b1  = (const float*)d_in[2];
    const float* lng = (const float*)d_in[3];
    const float* lnb = (const float*)d_in[4];
    const float* W2  = (const float*)d_in[5];
    const float* b2  = (const float*)d_in[6];
    const float* ths = (const float*)d_in[7];
    const float* tht = (const float*)d_in[8];
    const float* Wc  = (const float*)d_in[9];
    const float* bc  = (const float*)d_in[10];
    float* out = (float*)d_out;
    float* ws  = (float*)d_ws;

    const int nrows = in_sizes[0] / 64;              // 131072
    const int nthreads = nrows * 2;                  // 2 lanes per row
    const int grid = (nthreads + 255) / 256;

    if (ws_size >= 540 * sizeof(float)) {
        setup_kernel<<<1, 384, 0, stream>>>(ths, tht, lng, lnb, W2, b2, ws);
        qmaml_kernel<true><<<grid, 256, 0, stream>>>(x, W1, b1, lng, lnb, W2, b2,
                                                     ths, tht, Wc, bc, ws, out, nrows);
    } else {
        qmaml_kernel<false><<<grid, 256, 0, stream>>>(x, W1, b1, lng, lnb, W2, b2,
                                                      ths, tht, Wc, bc, nullptr, out, nrows);
    }
}

// Round 15
// 140.580 us; speedup vs baseline: 1.0466x; 1.0028x over previous
//
#include <hip/hip_runtime.h>
#include <utility>

#define NQ 6
#define DIM 64

typedef float v2f __attribute__((ext_vector_type(2)));

namespace {

// ---- compile-time ring permutation (CNOT ladder), matching _ring_perm ----
constexpr int ring_entry(int r, int i) {
    int idx = i;
    for (int w = NQ - 1; w >= 0; --w) {
        int c = w;
        int t = (w + r) % NQ;
        int cbit = (idx >> (NQ - 1 - c)) & 1;
        idx ^= cbit << (NQ - 1 - t);
    }
    return idx;
}

// Logical->physical composed map after L rings (all rings are GF(2)-linear).
constexpr int Mc(int L, int i) {
    if (L == 1) return ring_entry(1, i);
    if (L == 2) return ring_entry(1, ring_entry(2, i));
    if (L == 3) return ring_entry(1, ring_entry(2, ring_entry(1, i)));
    return i;
}

constexpr int Minv(int L, int p) {
    for (int i = 0; i < DIM; ++i) if (Mc(L, i) == p) return i;
    return -1;
}

} // namespace

// ---- 1-instr VALU lane swap (pairs 2r<->2r+1): DPP quad_perm [1,0,3,2] ----
__device__ __forceinline__ float swap1(float v) {
    return __int_as_float(__builtin_amdgcn_mov_dpp(__float_as_int(v), 0xB1, 0xF, 0xF, true));
}
__device__ __forceinline__ v2f swap1v(v2f v) {
    v2f r; r.x = swap1(v.x); r.y = swap1(v.y); return r;
}
// generic quad_perm DPP on a v2f (CTL: 0xB1 = lane^1, 0x4E = lane^2)
template<int CTL>
__device__ __forceinline__ v2f dppv(v2f v) {
    v2f r;
    r.x = __int_as_float(__builtin_amdgcn_mov_dpp(__float_as_int(v.x), CTL, 0xF, 0xF, true));
    r.y = __int_as_float(__builtin_amdgcn_mov_dpp(__float_as_int(v.y), CTL, 0xF, 0xF, true));
    return r;
}
// (-v.y, v.x): the i* twiddle -- folds into VOP3P op_sel/neg on pk_fma
__device__ __forceinline__ v2f nsw(v2f v) {
    v2f r; r.x = -v.y; r.y = v.x; return r;
}

// ===== gate application in the fixed physical frame via composed maps =====
// 2 lanes per row: lane par = t&1 holds physical slots p = par*32 + l, l in [0,32).
// state: v2f sv[l] = (re, im) of slot l. logical i = Minv(L, p).

template<int LY, int W, int d, int... Ls>
__device__ __forceinline__ void wire_inlane(v2f* sv,
        float A0r, float A0i, float B0r, float B0i,
        float A1r, float A1i, float B1r, float B1i,
        std::integer_sequence<int, Ls...>) {
    (([&] {
        if constexpr (Ls < (Ls ^ d)) {
            constexpr int la = Ls, lb = Ls ^ d;
            constexpr int ra = (Minv(LY, la) >> (5 - W)) & 1;
            constexpr int rb = (Minv(LY, lb) >> (5 - W)) & 1;
            const float cAar = ra ? A1r : A0r, cAai = ra ? A1i : A0i;
            const float cBar = ra ? B1r : B0r, cBai = ra ? B1i : B0i;
            const float cAbr = rb ? A1r : A0r, cAbi = rb ? A1i : A0i;
            const float cBbr = rb ? B1r : B0r, cBbi = rb ? B1i : B0i;
            const v2f ma = sv[la], mb = sv[lb];
            const v2f na = nsw(ma), nb = nsw(mb);
            sv[la] = cAar*ma + cAai*na + cBar*mb + cBai*nb;
            sv[lb] = cAbr*mb + cAbi*nb + cBbr*ma + cBbi*na;
        }
    }()), ...);
}

template<int LY, int W, int... Ls>
__device__ __forceinline__ void wire_cross0(v2f* sv,
        float A0r, float A0i, float B0r, float B0i,
        float A1r, float A1i, float B1r, float B1i,
        std::integer_sequence<int, Ls...>) {
    (([&] {
        constexpr int r = (Minv(LY, Ls) >> (5 - W)) & 1;
        const float cAr = r ? A1r : A0r, cAi = r ? A1i : A0i;
        const float cBr = r ? B1r : B0r, cBi = r ? B1i : B0i;
        const v2f m = sv[Ls];
        const v2f t = swap1v(m);          // partner lane, same slot (old value)
        sv[Ls] = cAr*m + cAi*nsw(m) + cBr*t + cBi*nsw(t);
    }()), ...);
}

template<int LY, int W, int d, int... Ls>
__device__ __forceinline__ void wire_crossd(v2f* sv,
        float A0r, float A0i, float B0r, float B0i,
        float A1r, float A1i, float B1r, float B1i,
        std::integer_sequence<int, Ls...>) {
    (([&] {
        if constexpr (Ls < (Ls ^ d)) {
            constexpr int la = Ls, lb = Ls ^ d;
            constexpr int ra = (Minv(LY, la) >> (5 - W)) & 1;
            constexpr int rb = (Minv(LY, lb) >> (5 - W)) & 1;
            const float cAar = ra ? A1r : A0r, cAai = ra ? A1i : A0i;
            const float cBar = ra ? B1r : B0r, cBai = ra ? B1i : B0i;
            const float cAbr = rb ? A1r : A0r, cAbi = rb ? A1i : A0i;
            const float cBbr = rb ? B1r : B0r, cBbi = rb ? B1i : B0i;
            const v2f ma = sv[la], mb = sv[lb];
            const v2f ta = swap1v(mb);    // partner lane old [lb]
            const v2f tb = swap1v(ma);    // partner lane old [la]
            sv[la] = cAar*ma + cAai*nsw(ma) + cBar*ta + cBai*nsw(ta);
            sv[lb] = cAbr*mb + cAbi*nsw(mb) + cBbr*tb + cBbi*nsw(tb);
        }
    }()), ...);
}

template<int LY, int W>
__device__ __forceinline__ void wire_apply(v2f* sv,
        const float* __restrict__ g, bool par) {
    constexpr int D = Mc(LY, 1 << (5 - W));     // physical pair offset (linear map)
    constexpr bool cross = (D >> 5) & 1;
    constexpr int d = D & 31;
    constexpr bool cpar = (Minv(LY, 32) >> (5 - W)) & 1;  // role flips with parity

    float A0r, A0i, B0r, B0i, A1r, A1i, B1r, B1i;
    if constexpr (cpar) {
        A0r = par ? g[6] : g[0];  A0i = par ? g[7] : g[1];
        B0r = par ? g[4] : g[2];  B0i = par ? g[5] : g[3];
        A1r = par ? g[0] : g[6];  A1i = par ? g[1] : g[7];
        B1r = par ? g[2] : g[4];  B1i = par ? g[3] : g[5];
    } else {
        A0r = g[0]; A0i = g[1]; B0r = g[2]; B0i = g[3];
        A1r = g[6]; A1i = g[7]; B1r = g[4]; B1i = g[5];
    }
    if constexpr (!cross) {
        wire_inlane<LY, W, d>(sv, A0r, A0i, B0r, B0i, A1r, A1i, B1r, B1i,
                              std::make_integer_sequence<int, 32>{});
    } else if constexpr (d == 0) {
        wire_cross0<LY, W>(sv, A0r, A0i, B0r, B0i, A1r, A1i, B1r, B1i,
                           std::make_integer_sequence<int, 32>{});
    } else {
        wire_crossd<LY, W, d>(sv, A0r, A0i, B0r, B0i, A1r, A1i, B1r, B1i,
                              std::make_integer_sequence<int, 32>{});
    }
}

template<int LY>
__device__ __forceinline__ void layer_apply(v2f* sv,
        const float* __restrict__ g, bool par) {
    wire_apply<LY, 0>(sv, g,      par);
    wire_apply<LY, 1>(sv, g + 8,  par);
    wire_apply<LY, 2>(sv, g + 16, par);
    wire_apply<LY, 3>(sv, g + 24, par);
    wire_apply<LY, 4>(sv, g + 32, par);
    wire_apply<LY, 5>(sv, g + 40, par);
}

// ---- readout: fold full M3 into constexpr signs + one parity flip ----
template<int... Ls>
__device__ __forceinline__ void readout_impl(const v2f* sv, float* q,
                                             std::integer_sequence<int, Ls...>) {
    (([&] {
        constexpr int iv = Minv(3, Ls);
        const float pb = fmaf(sv[Ls].x, sv[Ls].x, sv[Ls].y * sv[Ls].y);
        q[0] += ((iv >> 5) & 1) ? -pb : pb;
        q[1] += ((iv >> 4) & 1) ? -pb : pb;
        q[2] += ((iv >> 3) & 1) ? -pb : pb;
        q[3] += ((iv >> 2) & 1) ? -pb : pb;
        q[4] += ((iv >> 1) & 1) ? -pb : pb;
        q[5] += ( iv       & 1) ? -pb : pb;
    }()), ...);
}

// ---- per-thread gate computation (fallback path only) ----
__device__ __forceinline__ void compute_gates6(const float* __restrict__ th, float* g) {
#pragma unroll
    for (int w = 0; w < NQ; ++w) {
        const float phi = th[w*3+0], theta = th[w*3+1], omega = th[w*3+2];
        float s, c, sa, ca, sb, cb;
        __sincosf(0.5f * theta, &s, &c);
        __sincosf(0.5f * (phi + omega), &sa, &ca);
        __sincosf(0.5f * (phi - omega), &sb, &cb);
        g[w*8+0] =  ca * c;  g[w*8+1] = -sa * c;
        g[w*8+2] = -cb * s;  g[w*8+3] = -sb * s;
        g[w*8+4] =  cb * s;  g[w*8+5] = -sb * s;
        g[w*8+6] =  ca * c;  g[w*8+7] =  sa * c;
    }
}

// ---- setup: gates (18x8) + Gt[j][m] = ln_g[j]*W2[m][j] (64x6) + C1/C2 ----
// ws floats: [0,144) gates, [144,528) Gt (j*6+m), [528,534) C1, [534,540) C2+b2
__global__ void setup_kernel(const float* __restrict__ th_s, const float* __restrict__ th_t,
                             const float* __restrict__ ln_g, const float* __restrict__ ln_b,
                             const float* __restrict__ W2, const float* __restrict__ b2,
                             float* __restrict__ ws) {
    const int t = threadIdx.x;
    if (t < 18) {
        const int l = t / 6, w = t % 6;
        const float* th = (l < 2) ? (th_s + (l * 6 + w) * 3) : (th_t + w * 3);
        const float phi = th[0], theta = th[1], omega = th[2];
        float s, c, sa, ca, sb, cb;
        sincosf(0.5f * theta, &s, &c);
        sincosf(0.5f * (phi + omega), &sa, &ca);
        sincosf(0.5f * (phi - omega), &sb, &cb);
        float* g = ws + t * 8;
        g[0] =  ca * c;  g[1] = -sa * c;
        g[2] = -cb * s;  g[3] = -sb * s;
        g[4] =  cb * s;  g[5] = -sb * s;
        g[6] =  ca * c;  g[7] =  sa * c;
    }
    if (t < 384) {
        const int j = t / 6, m = t % 6;
        ws[144 + t] = ln_g[j] * W2[m * 64 + j];
    }
    if (t < 6) {
        float c1 = 0.f, c2 = 0.f;
        for (int j = 0; j < 64; ++j) {
            c1 += ln_g[j] * W2[t * 64 + j];
            c2 += ln_b[j] * W2[t * 64 + j];
        }
        ws[528 + t] = c1;
        ws[534 + t] = c2 + b2[t];
    }
}

template<bool USE_WS>
__global__ __launch_bounds__(256, 4)   // 128-VGPR budget: allocator fits naturally, no spill
void qmaml_kernel(
    const float* __restrict__ x,  const float* __restrict__ W1, const float* __restrict__ b1,
    const float* __restrict__ ln_g, const float* __restrict__ ln_b,
    const float* __restrict__ W2, const float* __restrict__ b2,
    const float* __restrict__ th_s, const float* __restrict__ th_t,
    const float* __restrict__ Wc, const float* __restrict__ bc,
    const float* __restrict__ ws, float* __restrict__ out, int nrows) {

    // ---- stage W1 into LDS (16 KB) ----
    __shared__ float4 wl[1024];
    {
        const float4* wg = (const float4*)W1;
        const int tid = threadIdx.x;
#pragma unroll
        for (int k = 0; k < 4; ++k) wl[tid + (k << 8)] = wg[tid + (k << 8)];
    }
    __syncthreads();

    const int t   = blockIdx.x * 256 + threadIdx.x;
    const int row = t >> 1;
    const bool par = t & 1;            // = logical wire-0 bit of my half-state
    if (row >= nrows) return;

    const int qi = t & 3;              // position within the lane QUAD (2 rows)
    const int rA = (t >> 2) << 1;      // quad's even row; odd row = rA+1

    // ---- load x QUARTERS for BOTH rows of my quad (Tr=2 blocking) ----
    v2f xA[8], xB[8];
    {
        const float4* xpA = (const float4*)(x + (long)rA * 64 + (qi << 4));
        const float4* xpB = (const float4*)(x + (long)(rA + 1) * 64 + (qi << 4));
#pragma unroll
        for (int k = 0; k < 4; ++k) {
            const float4 a = xpA[k];
            const float4 b = xpB[k];
            xA[2*k].x   = a.x; xA[2*k].y   = a.y;
            xA[2*k+1].x = a.z; xA[2*k+1].y = a.w;
            xB[2*k].x   = b.x; xB[2*k].y   = b.y;
            xB[2*k+1].x = b.z; xB[2*k+1].y = b.w;
        }
    }

    // ---- quad-blocked matvec: each lane reads a QUARTER W1 row per j ----
    v2f A2[3]; A2[0] = 0.f; A2[1] = 0.f; A2[2] = 0.f;
    float A[6]  = {0.f, 0.f, 0.f, 0.f, 0.f, 0.f};
    float C1[6] = {0.f, 0.f, 0.f, 0.f, 0.f, 0.f};
    float C2[6] = {0.f, 0.f, 0.f, 0.f, 0.f, 0.f};
    float s = 0.f, s2 = 0.f;

    const bool rowB = qi & 2;          // my row is the quad's odd row
#pragma unroll 2
    for (int j = 0; j < 64; ++j) {
        const float4* wr = &wl[j * 16 + (qi << 2)];
        v2f a0; a0 = 0.f;
        v2f a1; a1 = 0.f;
        v2f b0; b0 = 0.f;
        v2f b1v; b1v = 0.f;
#pragma unroll
        for (int k = 0; k < 4; ++k) {
            const float4 w4 = wr[k];
            v2f w0; w0.x = w4.x; w0.y = w4.y;
            v2f w1; w1.x = w4.z; w1.y = w4.w;
            a0  = w0 * xA[2*k]     + a0;
            a1  = w1 * xA[2*k + 1] + a1;
            b0  = w0 * xB[2*k]     + b0;
            b1v = w1 * xB[2*k + 1] + b1v;
        }
        const v2f vA = a0 + a1;
        const v2f vB = b0 + b1v;
        v2f P; P.x = vA.x + vA.y; P.y = vB.x + vB.y;
        P = P + dppv<0xB1>(P);         // quad xor 1
        P = P + dppv<0x4E>(P);         // quad xor 2: all 4 lanes = (totA, totB)
        const float tot = rowB ? P.y : P.x;
        if constexpr (USE_WS) {
            const float acc = fmaxf(tot + b1[j], 0.f);
            s += acc; s2 = fmaf(acc, acc, s2);
            const v2f* Gt2 = (const v2f*)(ws + 144 + j * 6);   // 6 floats, 8B-aligned
            A2[0] = acc * Gt2[0] + A2[0];
            A2[1] = acc * Gt2[1] + A2[1];
            A2[2] = acc * Gt2[2] + A2[2];
        } else {
            const float acc = fmaxf(tot + b1[j], 0.f);
            s += acc; s2 = fmaf(acc, acc, s2);
            const float gj = ln_g[j], bj = ln_b[j];
#pragma unroll
            for (int m = 0; m < 6; ++m) {
                const float w2 = W2[m * 64 + j];
                const float gw = gj * w2;
                A[m]  = fmaf(acc, gw, A[m]);
                C1[m] += gw;
                C2[m] = fmaf(bj, w2, C2[m]);
            }
        }
    }
    if constexpr (USE_WS) {
        A[0] = A2[0].x; A[1] = A2[0].y; A[2] = A2[1].x;
        A[3] = A2[1].y; A[4] = A2[2].x; A[5] = A2[2].y;
    }

    const float mu  = s  * (1.f / 64.f);
    const float var = s2 * (1.f / 64.f) - mu * mu;
    const float inv = rsqrtf(var + 1e-5f);

    // ---- T5: favor waves in the pure-VALU quantum phase over LDS-stalled
    // matvec waves on the same SIMD (blocks start staggered -> phase mix).
    __builtin_amdgcn_s_setprio(1);

    // ---- z = tanh(...), per-wire (cos, sin) ----
    float vc[6], vsn[6];
#pragma unroll
    for (int m = 0; m < 6; ++m) {
        float c1v, c2v;
        if constexpr (USE_WS) { c1v = ws[528 + m]; c2v = ws[534 + m]; }
        else                  { c1v = C1[m];       c2v = C2[m] + b2[m]; }
        const float zp = inv * (A[m] - mu * c1v) + c2v;
        const float e  = __expf(2.f * zp);
        const float z  = 1.f - 2.f / (e + 1.f);
        const float half = 1.57079632679f * z;
        vsn[m] = __sinf(half);
        vc[m]  = __cosf(half);
    }

    float gf[48];
    const float* g0;
    if constexpr (USE_WS) g0 = ws;      // wave-uniform -> SGPR s_loads
    else { compute_gates6(th_s, gf); g0 = gf; }

    // ---- build my 32 amps IN PLACE as packed complex ----
    v2f sv[32];
    {
        const float a0r = par ? (g0[4]*vc[0] + g0[6]*vsn[0]) : (g0[0]*vc[0] + g0[2]*vsn[0]);
        const float a0i = par ? (g0[5]*vc[0] + g0[7]*vsn[0]) : (g0[1]*vc[0] + g0[3]*vsn[0]);
        v2f ga1; ga1.x = g0[8]  * vc[1] + g0[10] * vsn[1];
                 ga1.y = g0[9]  * vc[1] + g0[11] * vsn[1];
        v2f gb1; gb1.x = g0[12] * vc[1] + g0[14] * vsn[1];
                 gb1.y = g0[13] * vc[1] + g0[15] * vsn[1];
        sv[0] = a0r * ga1 + a0i * nsw(ga1);
        sv[1] = a0r * gb1 + a0i * nsw(gb1);
    }
    {   // wire2: 2 -> 4
        v2f ya; ya.x = g0[16]*vc[2] + g0[18]*vsn[2]; ya.y = g0[17]*vc[2] + g0[19]*vsn[2];
        v2f yb; yb.x = g0[20]*vc[2] + g0[22]*vsn[2]; yb.y = g0[21]*vc[2] + g0[23]*vsn[2];
        const v2f nya = nsw(ya), nyb = nsw(yb);
#pragma unroll
        for (int k = 3; k >= 0; --k) {
            const v2f h = sv[k >> 1];
            const v2f y  = (k & 1) ? yb  : ya;
            const v2f ny = (k & 1) ? nyb : nya;
            sv[k] = h.x * y + h.y * ny;
        }
    }
    {   // wire3: 4 -> 8
        v2f ya; ya.x = g0[24]*vc[3] + g0[26]*vsn[3]; ya.y = g0[25]*vc[3] + g0[27]*vsn[3];
        v2f yb; yb.x = g0[28]*vc[3] + g0[30]*vsn[3]; yb.y = g0[29]*vc[3] + g0[31]*vsn[3];
        const v2f nya = nsw(ya), nyb = nsw(yb);
#pragma unroll
        for (int k = 7; k >= 0; --k) {
            const v2f h = sv[k >> 1];
            const v2f y  = (k & 1) ? yb  : ya;
            const v2f ny = (k & 1) ? nyb : nya;
            sv[k] = h.x * y + h.y * ny;
        }
    }
    {   // wire4: 8 -> 16
        v2f ya; ya.x = g0[32]*vc[4] + g0[34]*vsn[4]; ya.y = g0[33]*vc[4] + g0[35]*vsn[4];
        v2f yb; yb.x = g0[36]*vc[4] + g0[38]*vsn[4]; yb.y = g0[37]*vc[4] + g0[39]*vsn[4];
        const v2f nya = nsw(ya), nyb = nsw(yb);
#pragma unroll
        for (int k = 15; k >= 0; --k) {
            const v2f h = sv[k >> 1];
            const v2f y  = (k & 1) ? yb  : ya;
            const v2f ny = (k & 1) ? nyb : nya;
            sv[k] = h.x * y + h.y * ny;
        }
    }
    {   // wire5: 16 -> 32
        v2f ya; ya.x = g0[40]*vc[5] + g0[42]*vsn[5]; ya.y = g0[41]*vc[5] + g0[43]*vsn[5];
        v2f yb; yb.x = g0[44]*vc[5] + g0[46]*vsn[5]; yb.y = g0[45]*vc[5] + g0[47]*vsn[5];
        const v2f nya = nsw(ya), nyb = nsw(yb);
#pragma unroll
        for (int k = 31; k >= 0; --k) {
            const v2f h = sv[k >> 1];
            const v2f y  = (k & 1) ? yb  : ya;
            const v2f ny = (k & 1) ? nyb : nya;
            sv[k] = h.x * y + h.y * ny;
        }
    }

    // ---- layers act through composed maps; NO physical permutations ----
    if constexpr (USE_WS) {
        layer_apply<1>(sv, ws + 48, par);
        layer_apply<2>(sv, ws + 96, par);
    } else {
        compute_gates6(th_s + 18, gf);
        layer_apply<1>(sv, gf, par);
        compute_gates6(th_t, gf);
        layer_apply<2>(sv, gf, par);
    }

    // ---- <Z_w> readout through M3 ----
    float q[6] = {0.f, 0.f, 0.f, 0.f, 0.f, 0.f};
    readout_impl(sv, q, std::make_integer_sequence<int, 32>{});

    __builtin_amdgcn_s_setprio(0);

    const float pm = par ? -1.f : 1.f;
    constexpr int invC = Minv(3, 32);   // parity contribution to M3^-1
#pragma unroll
    for (int w = 0; w < 6; ++w) {
        float tq = q[w];
        if ((invC >> (5 - w)) & 1) tq *= pm;
        q[w] = tq + swap1(tq);
    }

    // ---- head: out = q @ Wc^T + bc (split store across the lane pair) ----
    float o[5];
#pragma unroll
    for (int n = 0; n < 5; ++n) {
        float v = bc[n];
#pragma unroll
        for (int w = 0; w < 6; ++w) v = fmaf(q[w], Wc[n * 6 + w], v);
        o[n] = v;
    }
    float* orow = out + (long)row * 5;
    if (!par) { orow[0] = o[0]; orow[1] = o[1]; orow[2] = o[2]; }
    else      { orow[3] = o[3]; orow[4] = o[4]; }
}

extern "C" void kernel_launch(void* const* d_in, const int* in_sizes, int n_in,
                              void* d_out, int out_size, void* d_ws, size_t ws_size,
                              hipStream_t stream) {
    const float* x   = (const float*)d_in[0];
    const float* W1  = (const float*)d_in[1];
    const float* b1  = (const float*)d_in[2];
    const float* lng = (const float*)d_in[3];
    const float* lnb = (const float*)d_in[4];
    const float* W2  = (const float*)d_in[5];
    const float* b2  = (const float*)d_in[6];
    const float* ths = (const float*)d_in[7];
    const float* tht = (const float*)d_in[8];
    const float* Wc  = (const float*)d_in[9];
    const float* bc  = (const float*)d_in[10];
    float* out = (float*)d_out;
    float* ws  = (float*)d_ws;

    const int nrows = in_sizes[0] / 64;              // 131072
    const int nthreads = nrows * 2;                  // 2 lanes per row
    const int grid = (nthreads + 255) / 256;

    if (ws_size >= 540 * sizeof(float)) {
        setup_kernel<<<1, 384, 0, stream>>>(ths, tht, lng, lnb, W2, b2, ws);
        qmaml_kernel<true><<<grid, 256, 0, stream>>>(x, W1, b1, lng, lnb, W2, b2,
                                                     ths, tht, Wc, bc, ws, out, nrows);
    } else {
        qmaml_kernel<false><<<grid, 256, 0, stream>>>(x, W1, b1, lng, lnb, W2, b2,
                                                      ths, tht, Wc, bc, nullptr, out, nrows);
    }
}